// Round 2
// baseline (220.886 us; speedup 1.0000x reference)
//
#include <hip/hip_runtime.h>

// Chamfer distance, single-directional: queries = v_pred (d_in[1]), targets = v (d_in[0]).
// loss = (1/(B*N)) * sum_{b,i} min_j ||x_bi - y_bj||^2
//
// d2 = x2 + (y2 - 2 x.y). Stage targets as float4(-2yx, -2yy, -2yz, y2) in LDS
// (uniform-address broadcast reads), each thread keeps QPT=8 queries in registers,
// unroll 8 targets per group with min3-friendly trees (3 FMA + 0.5 min per pair).

#define BB 8
#define NN 16384   // queries per batch (v_pred)
#define MM 16384   // targets per batch (v)
#define TQ_SPLIT 8
#define T_TILE (MM / TQ_SPLIT)        // 2048 targets staged per block (32 KB LDS)
#define THREADS 512
#define QPT 8
#define Q_PER_BLOCK (THREADS * QPT)   // 4096
#define QC_SPLIT (NN / Q_PER_BLOCK)   // 4

__global__ __launch_bounds__(THREADS, 2)
void chamfer_min_kernel(const float* __restrict__ v,       // targets [B,M,3]
                        const float* __restrict__ vp,      // queries [B,N,3]
                        unsigned int* __restrict__ ws_min) // [B*N] f32 bits
{
    __shared__ float4 sh[T_TILE];
    const int bx  = blockIdx.x;
    const int tq  = bx & (TQ_SPLIT - 1);           // 3 bits
    const int qc  = (bx >> 3) & (QC_SPLIT - 1);    // 2 bits
    const int b   = bx >> 5;                       // 3 bits
    const int tid = threadIdx.x;

    // ---- stage target slice into LDS as (-2y, y^2) ----
    const float* vb = v + (size_t)b * MM * 3;
    for (int i = tid; i < T_TILE; i += THREADS) {
        const int t = tq * T_TILE + i;
        const float yx = vb[t * 3 + 0];
        const float yy = vb[t * 3 + 1];
        const float yz = vb[t * 3 + 2];
        const float y2 = yx * yx + yy * yy + yz * yz;
        sh[i] = make_float4(-2.f * yx, -2.f * yy, -2.f * yz, y2);
    }
    __syncthreads();

    // ---- load 8 queries into registers ----
    const float* vpb = vp + (size_t)b * NN * 3;
    float qx[QPT], qy[QPT], qz[QPT], mn[QPT];
    const int q0 = qc * Q_PER_BLOCK + tid;
#pragma unroll
    for (int j = 0; j < QPT; ++j) {
        const int q = q0 + j * THREADS;
        qx[j] = vpb[q * 3 + 0];
        qy[j] = vpb[q * 3 + 1];
        qz[j] = vpb[q * 3 + 2];
        mn[j] = 3.4e38f;
    }

    // ---- main loop: 8 targets per group, min3 trees ----
    for (int t0 = 0; t0 < T_TILE; t0 += 8) {
        float4 y[8];
#pragma unroll
        for (int k = 0; k < 8; ++k) y[k] = sh[t0 + k];
#pragma unroll
        for (int j = 0; j < QPT; ++j) {
            float d[8];
#pragma unroll
            for (int k = 0; k < 8; ++k)
                d[k] = fmaf(qx[j], y[k].x,
                        fmaf(qy[j], y[k].y,
                          fmaf(qz[j], y[k].z, y[k].w)));
            // min3-friendly trees: fminf(fminf(a,b),c) -> v_min3_f32
            const float a = fminf(fminf(d[0], d[1]), d[2]);
            const float c = fminf(fminf(d[3], d[4]), d[5]);
            const float e = fminf(fminf(d[6], d[7]), a);
            mn[j] = fminf(fminf(c, e), mn[j]);
        }
    }

    // ---- combine partial mins across target-slices (uint-bit min, d2 >= 0) ----
#pragma unroll
    for (int j = 0; j < QPT; ++j) {
        const int q = q0 + j * THREADS;
        const float x2 = qx[j] * qx[j] + qy[j] * qy[j] + qz[j] * qz[j];
        const float d2 = fmaxf(mn[j] + x2, 0.0f);  // clamp: bits-order == float-order
        atomicMin(&ws_min[(size_t)b * NN + q], __float_as_uint(d2));
    }
}

__global__ __launch_bounds__(256)
void chamfer_reduce_kernel(const unsigned int* __restrict__ ws_min,
                           float* __restrict__ out)
{
    const int tid = threadIdx.x;
    const int gid = blockIdx.x * 256 + tid;        // gid in [0, 32768)
    const uint4 u = ((const uint4*)ws_min)[gid];
    float s = __uint_as_float(u.x) + __uint_as_float(u.y) +
              __uint_as_float(u.z) + __uint_as_float(u.w);
#pragma unroll
    for (int off = 32; off; off >>= 1) s += __shfl_down(s, off, 64);
    __shared__ float wsum[4];
    if ((tid & 63) == 0) wsum[tid >> 6] = s;
    __syncthreads();
    if (tid == 0) {
        const float t = wsum[0] + wsum[1] + wsum[2] + wsum[3];
        atomicAdd(out, t * (1.0f / ((float)BB * (float)NN)));
    }
}

extern "C" void kernel_launch(void* const* d_in, const int* in_sizes, int n_in,
                              void* d_out, int out_size, void* d_ws, size_t ws_size,
                              hipStream_t stream) {
    const float* v  = (const float*)d_in[0];   // targets
    const float* vp = (const float*)d_in[1];   // queries
    float* out = (float*)d_out;
    unsigned int* ws_min = (unsigned int*)d_ws;  // B*N uints = 512 KB

    // init partial-min buffer to 0xFFFFFFFF (max uint) and output to 0
    hipMemsetAsync(ws_min, 0xFF, (size_t)BB * NN * sizeof(unsigned int), stream);
    hipMemsetAsync(out, 0, sizeof(float), stream);

    chamfer_min_kernel<<<BB * QC_SPLIT * TQ_SPLIT, THREADS, 0, stream>>>(v, vp, ws_min);
    chamfer_reduce_kernel<<<(BB * NN) / 1024, 256, 0, stream>>>(ws_min, out);
}

// Round 3
// 219.006 us; speedup vs baseline: 1.0086x; 1.0086x over previous
//
#include <hip/hip_runtime.h>

// Chamfer distance, single-directional: queries = v_pred (d_in[1]), targets = v (d_in[0]).
// loss = (1/(B*N)) * sum_{b,i} min_j ||x_bi - y_bj||^2
//
// d2 = x2 + (y2 - 2 x.y). Stage targets as float4(-2yx, -2yy, -2yz, y2) in LDS
// (uniform-address broadcast reads). Each thread holds QPT=8 queries in registers.
// Inner loop: 4 explicit target float4s (y0..y3, no indexable array -> no compiler
// restructuring), per query 12 FMA + 2 v_min3_f32 = 3.5 VALU ops/pair.
// Occupancy: 256 thr/block, 16 KB LDS, grid=1024 -> 4 blocks/CU = 4 waves/SIMD.

#define BB 8
#define NN 16384   // queries per batch (v_pred)
#define MM 16384   // targets per batch (v)
#define TQ_SPLIT 16
#define T_TILE (MM / TQ_SPLIT)        // 1024 targets staged per block (16 KB LDS)
#define THREADS 256
#define QPT 8
#define Q_PER_BLOCK (THREADS * QPT)   // 2048
#define QC_SPLIT (NN / Q_PER_BLOCK)   // 8

__global__ __launch_bounds__(THREADS, 4)
void chamfer_min_kernel(const float* __restrict__ v,       // targets [B,M,3]
                        const float* __restrict__ vp,      // queries [B,N,3]
                        unsigned int* __restrict__ ws_min) // [B*N] f32 bits
{
    __shared__ float4 sh[T_TILE];
    const int bx  = blockIdx.x;
    const int tq  = bx & (TQ_SPLIT - 1);           // 4 bits
    const int qc  = (bx >> 4) & (QC_SPLIT - 1);    // 3 bits
    const int b   = bx >> 7;                       // 3 bits
    const int tid = threadIdx.x;

    // ---- stage target slice into LDS as (-2y, y^2) ----
    const float* vb = v + (size_t)b * MM * 3;
    for (int i = tid; i < T_TILE; i += THREADS) {
        const int t = tq * T_TILE + i;
        const float yx = vb[t * 3 + 0];
        const float yy = vb[t * 3 + 1];
        const float yz = vb[t * 3 + 2];
        const float y2 = yx * yx + yy * yy + yz * yz;
        sh[i] = make_float4(-2.f * yx, -2.f * yy, -2.f * yz, y2);
    }
    __syncthreads();

    // ---- load 8 queries into registers ----
    const float* vpb = vp + (size_t)b * NN * 3;
    float qx[QPT], qy[QPT], qz[QPT], mn[QPT];
    const int q0 = qc * Q_PER_BLOCK + tid;
#pragma unroll
    for (int j = 0; j < QPT; ++j) {
        const int q = q0 + j * THREADS;
        qx[j] = vpb[q * 3 + 0];
        qy[j] = vpb[q * 3 + 1];
        qz[j] = vpb[q * 3 + 2];
        mn[j] = 3.4e38f;
    }

    // ---- main loop: 4 targets per iteration, explicit registers ----
    for (int t0 = 0; t0 < T_TILE; t0 += 4) {
        const float4 y0 = sh[t0 + 0];
        const float4 y1 = sh[t0 + 1];
        const float4 y2 = sh[t0 + 2];
        const float4 y3 = sh[t0 + 3];
#pragma unroll
        for (int j = 0; j < QPT; ++j) {
            const float d0 = fmaf(qx[j], y0.x, fmaf(qy[j], y0.y, fmaf(qz[j], y0.z, y0.w)));
            const float d1 = fmaf(qx[j], y1.x, fmaf(qy[j], y1.y, fmaf(qz[j], y1.z, y1.w)));
            const float d2 = fmaf(qx[j], y2.x, fmaf(qy[j], y2.y, fmaf(qz[j], y2.z, y2.w)));
            const float d3 = fmaf(qx[j], y3.x, fmaf(qy[j], y3.y, fmaf(qz[j], y3.z, y3.w)));
            const float a  = fminf(fminf(d0, d1), d2);     // v_min3_f32
            mn[j] = fminf(fminf(a, d3), mn[j]);            // v_min3_f32
        }
    }

    // ---- combine partial mins across target-slices (uint-bit min, d2 >= 0) ----
#pragma unroll
    for (int j = 0; j < QPT; ++j) {
        const int q = q0 + j * THREADS;
        const float x2 = qx[j] * qx[j] + qy[j] * qy[j] + qz[j] * qz[j];
        const float d2 = fmaxf(mn[j] + x2, 0.0f);  // clamp: bits-order == float-order
        atomicMin(&ws_min[(size_t)b * NN + q], __float_as_uint(d2));
    }
}

__global__ __launch_bounds__(256)
void chamfer_reduce_kernel(const unsigned int* __restrict__ ws_min,
                           float* __restrict__ out)
{
    const int tid = threadIdx.x;
    const int gid = blockIdx.x * 256 + tid;        // gid in [0, 32768)
    const uint4 u = ((const uint4*)ws_min)[gid];
    float s = __uint_as_float(u.x) + __uint_as_float(u.y) +
              __uint_as_float(u.z) + __uint_as_float(u.w);
#pragma unroll
    for (int off = 32; off; off >>= 1) s += __shfl_down(s, off, 64);
    __shared__ float wsum[4];
    if ((tid & 63) == 0) wsum[tid >> 6] = s;
    __syncthreads();
    if (tid == 0) {
        const float t = wsum[0] + wsum[1] + wsum[2] + wsum[3];
        atomicAdd(out, t * (1.0f / ((float)BB * (float)NN)));
    }
}

extern "C" void kernel_launch(void* const* d_in, const int* in_sizes, int n_in,
                              void* d_out, int out_size, void* d_ws, size_t ws_size,
                              hipStream_t stream) {
    const float* v  = (const float*)d_in[0];   // targets
    const float* vp = (const float*)d_in[1];   // queries
    float* out = (float*)d_out;
    unsigned int* ws_min = (unsigned int*)d_ws;  // B*N uints = 512 KB

    // init partial-min buffer to 0xFFFFFFFF (max uint) and output to 0
    hipMemsetAsync(ws_min, 0xFF, (size_t)BB * NN * sizeof(unsigned int), stream);
    hipMemsetAsync(out, 0, sizeof(float), stream);

    chamfer_min_kernel<<<BB * QC_SPLIT * TQ_SPLIT, THREADS, 0, stream>>>(v, vp, ws_min);
    chamfer_reduce_kernel<<<(BB * NN) / 1024, 256, 0, stream>>>(ws_min, out);
}

// Round 6
// 146.224 us; speedup vs baseline: 1.5106x; 1.4977x over previous
//
#include <hip/hip_runtime.h>

// Chamfer (single-directional) via split-fp16 MFMA.
// d2(q,t) = x2(q) + [ -2 x.y + y2 ](q,t);  x2 added after the min over t.
// Bilinear part: C = A*B with mfma_f32_32x32x16_f16, K=16 slots:
//   k0-2 : A=xh           B=-2*yh
//   k3-5 : A=32*xl        B=-2*yh/32        (power-of-2 scaling keeps f16 normal)
//   k6-8 : A=xh/32        B=-64*yl
//   k9   : A=1            B=y2h
//   k10  : A=1/32         B=32*y2l
//   k11-15: 0
// fp16 products are exact in the f32 accumulator; dropped xl*yl ~1e-6.
// Min over targets: elementwise v_min3_f32 across C-tiles, then butterfly
// shfl_xor reduce over the 32 cols, atomicMin merge across target slices.

typedef _Float16 half8 __attribute__((ext_vector_type(8)));
typedef float   f32x16 __attribute__((ext_vector_type(16)));

#define BB 8
#define NN 16384
#define MM 16384
#define TS_SPLIT 8
#define T_TGT   (MM / TS_SPLIT)      // 2048 targets per block
#define T_TILES (T_TGT / 32)         // 64 tiles -> 64 KB LDS of B-frags
#define QC_SPLIT 8
#define Q_CHUNK (NN / QC_SPLIT)      // 2048 queries per block
#define THREADS 512
#define WAVES   (THREADS / 64)       // 8
#define QT 4                         // q-tiles resident per wave
#define Q_ROUNDS (Q_CHUNK / (WAVES * QT * 32))   // 2

__global__ __launch_bounds__(THREADS, 1)
void chamfer_mfma_kernel(const float* __restrict__ v,        // targets [B,M,3]
                         const float* __restrict__ vp,       // queries [B,N,3]
                         unsigned int* __restrict__ ws)      // [B*N] f32 bits
{
    __shared__ half8 shB[T_TILES * 64];

    const int tid  = threadIdx.x;
    const int lane = tid & 63;
    const int l31  = lane & 31;
    const int hi   = lane >> 5;
    const int wav  = tid >> 6;

    const int bx = blockIdx.x;
    const int ts = bx & (TS_SPLIT - 1);
    const int qc = (bx >> 3) & (QC_SPLIT - 1);
    const int b  = bx >> 6;

    // ---------- stage B fragments (targets) into LDS ----------
    const float* vb = v + (size_t)b * MM * 3;
    for (int tile = wav; tile < T_TILES; tile += WAVES) {
        const int t = ts * T_TGT + tile * 32 + l31;
        const float yx = vb[t*3+0], yy = vb[t*3+1], yz = vb[t*3+2];
        const float hx = (float)(_Float16)yx; const float lx = yx - hx;
        const float hy = (float)(_Float16)yy; const float ly = yy - hy;
        const float hz = (float)(_Float16)yz; const float lz = yz - hz;
        const float y2 = yx*yx + yy*yy + yz*yz;
        const float h2 = (float)(_Float16)y2; const float l2 = y2 - h2;
        half8 bf;
        if (hi == 0) {
            bf[0] = (_Float16)(-2.f      * hx);
            bf[1] = (_Float16)(-2.f      * hy);
            bf[2] = (_Float16)(-2.f      * hz);
            bf[3] = (_Float16)(-0.0625f  * hx);   // -2/32 * yh
            bf[4] = (_Float16)(-0.0625f  * hy);
            bf[5] = (_Float16)(-0.0625f  * hz);
            bf[6] = (_Float16)(-64.f     * lx);
            bf[7] = (_Float16)(-64.f     * ly);
        } else {
            bf[0] = (_Float16)(-64.f     * lz);
            bf[1] = (_Float16)h2;
            bf[2] = (_Float16)(32.f      * l2);
            bf[3] = (_Float16)0.f; bf[4] = (_Float16)0.f;
            bf[5] = (_Float16)0.f; bf[6] = (_Float16)0.f; bf[7] = (_Float16)0.f;
        }
        shB[tile * 64 + lane] = bf;
    }
    __syncthreads();

    const float* vq = vp + (size_t)b * NN * 3;
    unsigned int* wsb = ws + (size_t)b * NN;

    for (int rnd = 0; rnd < Q_ROUNDS; ++rnd) {
        // ---------- build QT A fragments (queries) ----------
        half8 a0, a1, a2, a3;
        float x20, x21, x22, x23;
        int   qb0, qb1, qb2, qb3;
        auto buildA = [&](int j, half8& af, float& x2v, int& qbv) {
            const int qt = rnd * (WAVES * QT) + wav * QT + j;
            qbv = qc * Q_CHUNK + qt * 32;
            const int q = qbv + l31;
            const float x = vq[q*3+0], y = vq[q*3+1], z = vq[q*3+2];
            const float hx = (float)(_Float16)x; const float lx = x - hx;
            const float hy = (float)(_Float16)y; const float ly = y - hy;
            const float hz = (float)(_Float16)z; const float lz = z - hz;
            x2v = x*x + y*y + z*z;
            half8 t_;
            if (hi == 0) {
                t_[0] = (_Float16)hx; t_[1] = (_Float16)hy; t_[2] = (_Float16)hz;
                t_[3] = (_Float16)(32.f * lx);
                t_[4] = (_Float16)(32.f * ly);
                t_[5] = (_Float16)(32.f * lz);
                t_[6] = (_Float16)(0.03125f * hx);
                t_[7] = (_Float16)(0.03125f * hy);
            } else {
                t_[0] = (_Float16)(0.03125f * hz);
                t_[1] = (_Float16)1.f;
                t_[2] = (_Float16)0.03125f;
                t_[3] = (_Float16)0.f; t_[4] = (_Float16)0.f;
                t_[5] = (_Float16)0.f; t_[6] = (_Float16)0.f; t_[7] = (_Float16)0.f;
            }
            af = t_;
        };
        buildA(0, a0, x20, qb0);
        buildA(1, a1, x21, qb1);
        buildA(2, a2, x22, qb2);
        buildA(3, a3, x23, qb3);

        f32x16 r0, r1, r2, r3, Z;
#pragma unroll
        for (int e = 0; e < 16; ++e) {
            Z[e] = 0.f;
            r0[e] = 3.4e38f; r1[e] = 3.4e38f; r2[e] = 3.4e38f; r3[e] = 3.4e38f;
        }

        // ---------- main loop: 2 target tiles per iter ----------
        for (int tt = 0; tt < T_TILES; tt += 2) {
            const half8 bA = shB[tt * 64 + lane];
            const half8 bBv = shB[(tt + 1) * 64 + lane];

            f32x16 c00 = __builtin_amdgcn_mfma_f32_32x32x16_f16(a0, bA,  Z, 0, 0, 0);
            f32x16 c01 = __builtin_amdgcn_mfma_f32_32x32x16_f16(a0, bBv, Z, 0, 0, 0);
            f32x16 c10 = __builtin_amdgcn_mfma_f32_32x32x16_f16(a1, bA,  Z, 0, 0, 0);
            f32x16 c11 = __builtin_amdgcn_mfma_f32_32x32x16_f16(a1, bBv, Z, 0, 0, 0);
#pragma unroll
            for (int e = 0; e < 16; ++e) r0[e] = fminf(fminf(r0[e], c00[e]), c01[e]);
#pragma unroll
            for (int e = 0; e < 16; ++e) r1[e] = fminf(fminf(r1[e], c10[e]), c11[e]);

            f32x16 c20 = __builtin_amdgcn_mfma_f32_32x32x16_f16(a2, bA,  Z, 0, 0, 0);
            f32x16 c21 = __builtin_amdgcn_mfma_f32_32x32x16_f16(a2, bBv, Z, 0, 0, 0);
            f32x16 c30 = __builtin_amdgcn_mfma_f32_32x32x16_f16(a3, bA,  Z, 0, 0, 0);
            f32x16 c31 = __builtin_amdgcn_mfma_f32_32x32x16_f16(a3, bBv, Z, 0, 0, 0);
#pragma unroll
            for (int e = 0; e < 16; ++e) r2[e] = fminf(fminf(r2[e], c20[e]), c21[e]);
#pragma unroll
            for (int e = 0; e < 16; ++e) r3[e] = fminf(fminf(r3[e], c30[e]), c31[e]);
        }

        // ---------- epilogue: reduce cols (targets), write per-query min ----------
        auto finish = [&](f32x16 rr, float x2v, int qbv) {
            // butterfly min across the 32 cols (lanes within each 32-half)
#pragma unroll
            for (int m = 1; m < 32; m <<= 1) {
#pragma unroll
                for (int e = 0; e < 16; ++e)
                    rr[e] = fminf(rr[e], __shfl_xor(rr[e], m, 64));
            }
            // select the reg holding row == l31 for this lane's half
            float val = rr[0];
#pragma unroll
            for (int e = 1; e < 16; ++e) {
                const int erow = (e & 3) + 8 * (e >> 2) + 4 * hi;
                val = (l31 == erow) ? rr[e] : val;
            }
            // rows with bit2 == hi live in this half; one writer lane per row
            if (((lane >> 2) & 1) == hi) {
                const float d2 = fmaxf(val + x2v, 0.f);
                atomicMin(&wsb[qbv + l31], __float_as_uint(d2));
            }
        };
        finish(r0, x20, qb0);
        finish(r1, x21, qb1);
        finish(r2, x22, qb2);
        finish(r3, x23, qb3);
    }
}

__global__ __launch_bounds__(256)
void chamfer_reduce_kernel(const unsigned int* __restrict__ ws_min,
                           float* __restrict__ out)
{
    const int tid = threadIdx.x;
    const int gid = blockIdx.x * 256 + tid;        // [0, 32768)
    const uint4 u = ((const uint4*)ws_min)[gid];
    float s = __uint_as_float(u.x) + __uint_as_float(u.y) +
              __uint_as_float(u.z) + __uint_as_float(u.w);
#pragma unroll
    for (int off = 32; off; off >>= 1) s += __shfl_down(s, off, 64);
    __shared__ float wsum[4];
    if ((tid & 63) == 0) wsum[tid >> 6] = s;
    __syncthreads();
    if (tid == 0) {
        const float t = wsum[0] + wsum[1] + wsum[2] + wsum[3];
        atomicAdd(out, t * (1.0f / ((float)BB * (float)NN)));
    }
}

extern "C" void kernel_launch(void* const* d_in, const int* in_sizes, int n_in,
                              void* d_out, int out_size, void* d_ws, size_t ws_size,
                              hipStream_t stream) {
    const float* v  = (const float*)d_in[0];   // targets
    const float* vp = (const float*)d_in[1];   // queries
    float* out = (float*)d_out;
    unsigned int* ws_min = (unsigned int*)d_ws;  // B*N uints = 512 KB

    hipMemsetAsync(ws_min, 0xFF, (size_t)BB * NN * sizeof(unsigned int), stream);
    hipMemsetAsync(out, 0, sizeof(float), stream);

    chamfer_mfma_kernel<<<BB * QC_SPLIT * TS_SPLIT, THREADS, 0, stream>>>(v, vp, ws_min);
    chamfer_reduce_kernel<<<(BB * NN) / 1024, 256, 0, stream>>>(ws_min, out);
}

// Round 8
// 128.379 us; speedup vs baseline: 1.7206x; 1.1390x over previous
//
#include <hip/hip_runtime.h>

// Chamfer (single-directional) via split-fp16 MFMA, operand-swapped.
// d2(q,t) = x2(q) + [ -2 x.y + y2 ](q,t);  x2 added after the min over t.
// A = target fragments (rows), B = query fragments (cols):
//   C[row=target][col=query]; each lane holds 16 target-rows x 1 query-col,
//   so the min over targets folds in-register to a scalar (8 v_min3 / MFMA).
// K=16 slot scheme (HW-validated round 6, absmax 0.0):
//   k0-2 : T=-2*yh         Q=xh
//   k3-5 : T=-2*yh/32      Q=32*xl
//   k6-8 : T=-64*yl        Q=xh/32
//   k9   : T=y2h           Q=1
//   k10  : T=32*y2l        Q=1/32
// Single kernel: each block covers ALL targets via 8 LDS restage passes;
// no ws buffer, no atomicMin, one atomicAdd per block.

typedef _Float16 half8 __attribute__((ext_vector_type(8)));
typedef float   f32x16 __attribute__((ext_vector_type(16)));

#define BB 8
#define NN 16384
#define MM 16384
#define THREADS 256
#define WAVES   (THREADS / 64)            // 4
#define QT 2                              // q-tiles per wave
#define Q_PER_BLOCK (WAVES * QT * 32)     // 256
#define QC_SPLIT (NN / Q_PER_BLOCK)       // 64
#define PASS_TILES 64                     // target tiles staged per pass (64 KB)
#define PASS_TGT  (PASS_TILES * 32)       // 2048
#define NPASS     (MM / PASS_TGT)         // 8

__device__ inline float min3f(float a, float b, float c) {
    return fminf(fminf(a, b), c);         // v_min3_f32
}
__device__ inline float fold16(const f32x16 c, float r) {
    const float t0 = min3f(c[0],  c[1],  c[2]);
    const float t1 = min3f(c[3],  c[4],  c[5]);
    const float t2 = min3f(c[6],  c[7],  c[8]);
    const float t3 = min3f(c[9],  c[10], c[11]);
    const float t4 = min3f(c[12], c[13], c[14]);
    return min3f(min3f(t0, t1, t2), min3f(t3, t4, c[15]), r);
}

__global__ __launch_bounds__(THREADS, 2)
void chamfer_kernel(const float* __restrict__ v,    // targets [B,M,3]
                    const float* __restrict__ vp,   // queries [B,N,3]
                    float* __restrict__ out)
{
    __shared__ half8 shA[PASS_TILES * 64];          // exactly 64 KB

    const int tid  = threadIdx.x;
    const int lane = tid & 63;
    const int l31  = lane & 31;
    const int hi   = lane >> 5;
    const int wav  = tid >> 6;

    const int bx = blockIdx.x;
    const int qc = bx & (QC_SPLIT - 1);             // 6 bits
    const int b  = bx >> 6;                         // 3 bits

    const float* vb = v  + (size_t)b * MM * 3;
    const float* vq = vp + (size_t)b * NN * 3;

    // ---------- build QT query fragments (B operand) ----------
    half8 b0, b1;
    float x20, x21;
    {
        const int qt0 = (qc * Q_PER_BLOCK) / 32 + wav * QT;
#pragma unroll
        for (int j = 0; j < QT; ++j) {
            const int q = (qt0 + j) * 32 + l31;
            const float x = vq[q*3+0], y = vq[q*3+1], z = vq[q*3+2];
            const float hx = (float)(_Float16)x; const float lx = x - hx;
            const float hy = (float)(_Float16)y; const float ly = y - hy;
            const float hz = (float)(_Float16)z; const float lz = z - hz;
            const float x2 = x*x + y*y + z*z;
            half8 t_;
            if (hi == 0) {
                t_[0] = (_Float16)hx; t_[1] = (_Float16)hy; t_[2] = (_Float16)hz;
                t_[3] = (_Float16)(32.f * lx);
                t_[4] = (_Float16)(32.f * ly);
                t_[5] = (_Float16)(32.f * lz);
                t_[6] = (_Float16)(0.03125f * hx);
                t_[7] = (_Float16)(0.03125f * hy);
            } else {
                t_[0] = (_Float16)(0.03125f * hz);
                t_[1] = (_Float16)1.f;
                t_[2] = (_Float16)0.03125f;
                t_[3] = (_Float16)0.f; t_[4] = (_Float16)0.f;
                t_[5] = (_Float16)0.f; t_[6] = (_Float16)0.f; t_[7] = (_Float16)0.f;
            }
            if (j == 0) { b0 = t_; x20 = x2; } else { b1 = t_; x21 = x2; }
        }
    }

    f32x16 Z;
#pragma unroll
    for (int e = 0; e < 16; ++e) Z[e] = 0.f;

    float r0 = 3.4e38f, r1 = 3.4e38f;

    // ---------- passes over target chunks ----------
    for (int pass = 0; pass < NPASS; ++pass) {
        __syncthreads();   // previous pass's reads complete
        // stage 2048 targets (A-operand fragments), 8 per thread
#pragma unroll
        for (int k = 0; k < 8; ++k) {
            const int tl = tid + k * THREADS;       // 0..2047
            const int t  = pass * PASS_TGT + tl;
            const float yx = vb[t*3+0], yy = vb[t*3+1], yz = vb[t*3+2];
            const float hx = (float)(_Float16)yx; const float lx = yx - hx;
            const float hy = (float)(_Float16)yy; const float ly = yy - hy;
            const float hz = (float)(_Float16)yz; const float lz = yz - hz;
            const float y2 = yx*yx + yy*yy + yz*yz;
            const float h2 = (float)(_Float16)y2; const float l2 = y2 - h2;
            half8 f0, f1;
            f0[0] = (_Float16)(-2.f     * hx);
            f0[1] = (_Float16)(-2.f     * hy);
            f0[2] = (_Float16)(-2.f     * hz);
            f0[3] = (_Float16)(-0.0625f * hx);      // -2/32 * yh
            f0[4] = (_Float16)(-0.0625f * hy);
            f0[5] = (_Float16)(-0.0625f * hz);
            f0[6] = (_Float16)(-64.f    * lx);
            f0[7] = (_Float16)(-64.f    * ly);
            f1[0] = (_Float16)(-64.f    * lz);
            f1[1] = (_Float16)h2;
            f1[2] = (_Float16)(32.f     * l2);
            f1[3] = (_Float16)0.f; f1[4] = (_Float16)0.f;
            f1[5] = (_Float16)0.f; f1[6] = (_Float16)0.f; f1[7] = (_Float16)0.f;
            const int tile = tl >> 5, l = tl & 31;
            shA[tile * 64 + l]      = f0;
            shA[tile * 64 + 32 + l] = f1;
        }
        __syncthreads();

        // ---------- pipelined compute: fold tile t while t+1 in flight ----------
        half8 fA = shA[0 * 64 + lane];
        f32x16 cA0 = __builtin_amdgcn_mfma_f32_32x32x16_f16(fA, b0, Z, 0, 0, 0);
        f32x16 cA1 = __builtin_amdgcn_mfma_f32_32x32x16_f16(fA, b1, Z, 0, 0, 0);
        half8 fB = shA[1 * 64 + lane];

        for (int tt = 0; tt < PASS_TILES - 2; tt += 2) {
            fA = shA[(tt + 2) * 64 + lane];
            const f32x16 cB0 = __builtin_amdgcn_mfma_f32_32x32x16_f16(fB, b0, Z, 0, 0, 0);
            const f32x16 cB1 = __builtin_amdgcn_mfma_f32_32x32x16_f16(fB, b1, Z, 0, 0, 0);
            r0 = fold16(cA0, r0);
            r1 = fold16(cA1, r1);
            fB = shA[(tt + 3) * 64 + lane];
            cA0 = __builtin_amdgcn_mfma_f32_32x32x16_f16(fA, b0, Z, 0, 0, 0);
            cA1 = __builtin_amdgcn_mfma_f32_32x32x16_f16(fA, b1, Z, 0, 0, 0);
            r0 = fold16(cB0, r0);
            r1 = fold16(cB1, r1);
        }
        // tail: cA holds tile 62, fB holds tile 63
        const f32x16 cB0 = __builtin_amdgcn_mfma_f32_32x32x16_f16(fB, b0, Z, 0, 0, 0);
        const f32x16 cB1 = __builtin_amdgcn_mfma_f32_32x32x16_f16(fB, b1, Z, 0, 0, 0);
        r0 = fold16(cA0, r0);
        r1 = fold16(cA1, r1);
        r0 = fold16(cB0, r0);
        r1 = fold16(cB1, r1);
    }

    // ---------- epilogue: merge hi halves, add x2, block-sum, one atomicAdd ----------
    const float m0 = fminf(r0, __shfl_xor(r0, 32, 64));
    const float m1 = fminf(r1, __shfl_xor(r1, 32, 64));
    const float d0 = fmaxf(m0 + x20, 0.f);
    const float d1 = fmaxf(m1 + x21, 0.f);
    float s = (hi == 0) ? (d0 + d1) : 0.f;
#pragma unroll
    for (int off = 32; off; off >>= 1) s += __shfl_down(s, off, 64);

    __syncthreads();                       // compute done; reuse shA as scratch
    float* fs = (float*)shA;
    if (lane == 0) fs[wav] = s;
    __syncthreads();
    if (tid == 0) {
        const float t = fs[0] + fs[1] + fs[2] + fs[3];
        atomicAdd(out, t * (1.0f / ((float)BB * (float)NN)));
    }
}

extern "C" void kernel_launch(void* const* d_in, const int* in_sizes, int n_in,
                              void* d_out, int out_size, void* d_ws, size_t ws_size,
                              hipStream_t stream) {
    const float* v  = (const float*)d_in[0];   // targets
    const float* vp = (const float*)d_in[1];   // queries
    float* out = (float*)d_out;

    hipMemsetAsync(out, 0, sizeof(float), stream);
    chamfer_kernel<<<BB * QC_SPLIT, THREADS, 0, stream>>>(v, vp, out);
}

// Round 11
// 127.310 us; speedup vs baseline: 1.7350x; 1.0084x over previous
//
#include <hip/hip_runtime.h>

// Chamfer (single-directional) via split-fp16 MFMA, target-split waves.
// d2(q,t) = x2(q) + [ -2 x.y + y2 ](q,t);  x2 added after the min over t.
// A = target fragments (rows), B = query fragments (cols): each lane's 16
// C elements are 16 target-rows of ONE query-col -> min folds in-register.
// Fold uses fminf chains ONLY (rounds 6/8 proven absmax 0.0). Round 9's
// inline-asm v_min3_f32 read MFMA results without hazard waits -> garbage.
// K=16 slot scheme (HW-validated rounds 6/8, absmax 0.0):
//   k0-2: T=-2*yh Q=xh | k3-5: T=-2*yh/32 Q=32*xl | k6-8: T=-64*yl Q=xh/32
//   k9: T=y2h Q=1 | k10: T=32*y2l Q=1/32
// Structure: 512 thr = 8 waves; waves 0-3 -> target half 0, waves 4-7 ->
// half 1 (same queries). 8 passes x 64KB LDS (32 tiles/half). Fragments
// prebuilt into d_ws by a prep kernel (fallback: in-kernel rebuild).

typedef _Float16 half8 __attribute__((ext_vector_type(8)));
typedef float   f32x16 __attribute__((ext_vector_type(16)));

#define BB 8
#define NN 16384
#define MM 16384
#define THREADS 512
#define QT 2
#define Q_PER_BLOCK 256                    // 4 q-waves * QT * 32
#define QC_SPLIT (NN / Q_PER_BLOCK)        // 64
#define NPASS 8
#define HALF_UNITS 2048                    // 32 tiles * 64 half8 per half-buffer
#define WS_UNITS_PER_B 32768               // 512 tiles * 64
#define WS_BYTES ((size_t)BB * WS_UNITS_PER_B * 16)

__device__ inline float min3f(float a, float b, float c) {
    return fminf(fminf(a, b), c);          // compiler may fuse to v_min3_f32
}
__device__ inline float fold16(const f32x16 c, float r) {
    const float t0 = min3f(c[0],  c[1],  c[2]);
    const float t1 = min3f(c[3],  c[4],  c[5]);
    const float t2 = min3f(c[6],  c[7],  c[8]);
    const float t3 = min3f(c[9],  c[10], c[11]);
    const float t4 = min3f(c[12], c[13], c[14]);
    return min3f(min3f(t0, t1, t2), min3f(t3, t4, c[15]), r);
}

__device__ inline void make_frags(float yx, float yy, float yz,
                                  half8& f0, half8& f1) {
    const float hx = (float)(_Float16)yx; const float lx = yx - hx;
    const float hy = (float)(_Float16)yy; const float ly = yy - hy;
    const float hz = (float)(_Float16)yz; const float lz = yz - hz;
    const float y2 = yx*yx + yy*yy + yz*yz;
    const float h2 = (float)(_Float16)y2; const float l2 = y2 - h2;
    f0[0] = (_Float16)(-2.f     * hx);
    f0[1] = (_Float16)(-2.f     * hy);
    f0[2] = (_Float16)(-2.f     * hz);
    f0[3] = (_Float16)(-0.0625f * hx);
    f0[4] = (_Float16)(-0.0625f * hy);
    f0[5] = (_Float16)(-0.0625f * hz);
    f0[6] = (_Float16)(-64.f    * lx);
    f0[7] = (_Float16)(-64.f    * ly);
    f1[0] = (_Float16)(-64.f    * lz);
    f1[1] = (_Float16)h2;
    f1[2] = (_Float16)(32.f     * l2);
    f1[3] = (_Float16)0.f; f1[4] = (_Float16)0.f;
    f1[5] = (_Float16)0.f; f1[6] = (_Float16)0.f; f1[7] = (_Float16)0.f;
}

__global__ __launch_bounds__(256)
void prep_kernel(const float* __restrict__ v, half8* __restrict__ wsf) {
    const int t  = blockIdx.x * 256 + threadIdx.x;   // [0, BB*MM)
    const int b  = t >> 14;
    const int ti = t & (MM - 1);
    const float* p = v + (size_t)b * MM * 3 + (size_t)ti * 3;
    half8 f0, f1;
    make_frags(p[0], p[1], p[2], f0, f1);
    const size_t base = (size_t)b * WS_UNITS_PER_B + (size_t)(ti >> 5) * 64 + (ti & 31);
    wsf[base]      = f0;
    wsf[base + 32] = f1;
}

template<int USE_WS>
__global__ __launch_bounds__(THREADS, 2)
void chamfer_kernel(const float* __restrict__ v,    // targets [B,M,3]
                    const float* __restrict__ vp,   // queries [B,N,3]
                    const half8* __restrict__ wsf,  // prebuilt fragments
                    float* __restrict__ out)
{
    __shared__ half8 shA[2 * HALF_UNITS];            // 64 KB

    const int tid  = threadIdx.x;
    const int lane = tid & 63;
    const int l31  = lane & 31;
    const int hi   = lane >> 5;
    const int wav  = tid >> 6;
    const int h    = wav >> 2;                       // target half
    const int qw   = wav & 3;                        // query wave id

    const int bx = blockIdx.x;
    const int qc = bx & (QC_SPLIT - 1);
    const int b  = bx >> 6;

    const float* vq = vp + (size_t)b * NN * 3;

    // ---------- build QT query fragments (B operand) ----------
    half8 b0, b1;
    float x20, x21;
    {
        const int qt0 = qc * (Q_PER_BLOCK / 32) + qw * QT;
#pragma unroll
        for (int j = 0; j < QT; ++j) {
            const int q = (qt0 + j) * 32 + l31;
            const float x = vq[q*3+0], y = vq[q*3+1], z = vq[q*3+2];
            const float hx = (float)(_Float16)x; const float lx = x - hx;
            const float hy = (float)(_Float16)y; const float ly = y - hy;
            const float hz = (float)(_Float16)z; const float lz = z - hz;
            const float x2 = x*x + y*y + z*z;
            half8 t_;
            if (hi == 0) {
                t_[0] = (_Float16)hx; t_[1] = (_Float16)hy; t_[2] = (_Float16)hz;
                t_[3] = (_Float16)(32.f * lx);
                t_[4] = (_Float16)(32.f * ly);
                t_[5] = (_Float16)(32.f * lz);
                t_[6] = (_Float16)(0.03125f * hx);
                t_[7] = (_Float16)(0.03125f * hy);
            } else {
                t_[0] = (_Float16)(0.03125f * hz);
                t_[1] = (_Float16)1.f;
                t_[2] = (_Float16)0.03125f;
                t_[3] = (_Float16)0.f; t_[4] = (_Float16)0.f;
                t_[5] = (_Float16)0.f; t_[6] = (_Float16)0.f; t_[7] = (_Float16)0.f;
            }
            if (j == 0) { b0 = t_; x20 = x2; } else { b1 = t_; x21 = x2; }
        }
    }

    f32x16 Z;
#pragma unroll
    for (int e = 0; e < 16; ++e) Z[e] = 0.f;

    float r0 = 3.4e38f, r1 = 3.4e38f;
    const half8* tile_base = shA + h * HALF_UNITS;

    for (int pass = 0; pass < NPASS; ++pass) {
        __syncthreads();   // previous pass's reads complete before overwrite
        if constexpr (USE_WS) {
            const uint4* g = (const uint4*)wsf + (size_t)b * WS_UNITS_PER_B;
            uint4* s = (uint4*)shA;
#pragma unroll
            for (int k = 0; k < 4; ++k)          // half 0
                s[tid + k * THREADS] = g[pass * 2048 + tid + k * THREADS];
#pragma unroll
            for (int k = 0; k < 4; ++k)          // half 1
                s[2048 + tid + k * THREADS] = g[16384 + pass * 2048 + tid + k * THREADS];
        } else {
            const float* vb = v + (size_t)b * MM * 3;
#pragma unroll
            for (int k = 0; k < 4; ++k) {
                const int tl    = tid + k * THREADS;       // [0,2048)
                const int hh    = tl >> 10;
                const int local = tl & 1023;
                const int t     = hh * 8192 + pass * 1024 + local;
                half8 f0, f1;
                make_frags(vb[t*3+0], vb[t*3+1], vb[t*3+2], f0, f1);
                const int unit = hh * HALF_UNITS + (local >> 5) * 64 + (local & 31);
                shA[unit]      = f0;
                shA[unit + 32] = f1;
            }
        }
        __syncthreads();

        // ---------- compute 32 tiles of this wave's half ----------
        half8 fA = tile_base[lane];
        for (int tt = 0; tt < 32; tt += 2) {
            half8 fB = tile_base[(tt + 1) * 64 + lane];
            f32x16 c0 = __builtin_amdgcn_mfma_f32_32x32x16_f16(fA, b0, Z, 0, 0, 0);
            f32x16 c1 = __builtin_amdgcn_mfma_f32_32x32x16_f16(fA, b1, Z, 0, 0, 0);
            r0 = fold16(c0, r0);
            r1 = fold16(c1, r1);
            fA = tile_base[(((tt + 2) & 31)) * 64 + lane];   // wraps on last iter (unused)
            c0 = __builtin_amdgcn_mfma_f32_32x32x16_f16(fB, b0, Z, 0, 0, 0);
            c1 = __builtin_amdgcn_mfma_f32_32x32x16_f16(fB, b1, Z, 0, 0, 0);
            r0 = fold16(c0, r0);
            r1 = fold16(c1, r1);
        }
    }

    // ---------- merge target halves across wave pairs, then reduce ----------
    __syncthreads();
    float* fs = (float*)shA;
    fs[wav * 128 + lane]      = r0;
    fs[wav * 128 + 64 + lane] = r1;
    __syncthreads();
    if (wav < 4) {
        r0 = fminf(fs[wav * 128 + lane],      fs[(wav + 4) * 128 + lane]);
        r1 = fminf(fs[wav * 128 + 64 + lane], fs[(wav + 4) * 128 + 64 + lane]);
        const float m0 = fminf(r0, __shfl_xor(r0, 32, 64));
        const float m1 = fminf(r1, __shfl_xor(r1, 32, 64));
        const float d0 = fmaxf(m0 + x20, 0.f);
        const float d1 = fmaxf(m1 + x21, 0.f);
        float s = (hi == 0) ? (d0 + d1) : 0.f;
#pragma unroll
        for (int off = 32; off; off >>= 1) s += __shfl_down(s, off, 64);
        if (lane == 0) fs[1024 + wav] = s;
    }
    __syncthreads();
    if (tid == 0) {
        const float t = fs[1024] + fs[1025] + fs[1026] + fs[1027];
        atomicAdd(out, t * (1.0f / ((float)BB * (float)NN)));
    }
}

extern "C" void kernel_launch(void* const* d_in, const int* in_sizes, int n_in,
                              void* d_out, int out_size, void* d_ws, size_t ws_size,
                              hipStream_t stream) {
    const float* v  = (const float*)d_in[0];   // targets
    const float* vp = (const float*)d_in[1];   // queries
    float* out = (float*)d_out;

    hipMemsetAsync(out, 0, sizeof(float), stream);
    if (ws_size >= WS_BYTES) {
        half8* wsf = (half8*)d_ws;
        prep_kernel<<<(BB * MM) / 256, 256, 0, stream>>>(v, wsf);
        chamfer_kernel<1><<<BB * QC_SPLIT, THREADS, 0, stream>>>(v, vp, wsf, out);
    } else {
        chamfer_kernel<0><<<BB * QC_SPLIT, THREADS, 0, stream>>>(v, vp, nullptr, out);
    }
}